// Round 1
// baseline (1483.467 us; speedup 1.0000x reference)
//
#include <hip/hip_runtime.h>
#include <math.h>

// Problem constants
constexpr int NF  = 119;   // filters
constexpr int D1  = 422;   // padded freq
constexpr int D2  = 1170;  // padded time
constexpr int P1  = 211;   // crop freq
constexpr int Q2  = 390;   // crop time
constexpr int ZSTRIDE = 392;                  // padded Z row (float2), 392*8=3136 B = 64B-aligned
constexpr float SNORM    = 2.0253575e-06f;    // 1/(422*1170)
constexpr float OUTSCALE = 1.2152144e-05f;    // 1/(211*390)

// ws layout (units of float2)
constexpr int OFF_W390  = 0;        // 390
constexpr int OFF_T1170 = 390;      // 780 : e^{+2pi i j/1170}, j<780
constexpr int OFF_W512  = 1170;     // 512 : e^{-2pi i j/512}
constexpr int OFF_CHIRP = 1682;     // 211 : W[n]=e^{+i pi n^2/211}
constexpr int OFF_U422  = 1893;     // 211 : e^{+2pi i p/422}
constexpr int OFF_BF    = 2104;     // 512 : FFT512(bwrap)/512
constexpr int OFF_BI    = 2616;     // 512 : FFT512(conj bwrap)/512
constexpr int OFF_X     = 3200;     // 422*1170 = 493740
constexpr int OFF_Z     = 496960;   // chunk * 422 * ZSTRIDE

__device__ inline float2 cmul(float2 a, float2 b) {
  return make_float2(fmaf(a.x, b.x, -(a.y * b.y)), fmaf(a.x, b.y, a.y * b.x));
}
__device__ inline float2 cmulc(float2 a, float2 b) {  // a * conj(b)
  return make_float2(fmaf(a.x, b.x, (a.y * b.y)), fmaf(a.y, b.x, -(a.x * b.y)));
}
__device__ inline void cfma(float2& c, float2 a, float2 b) {
  c.x = fmaf(a.x, b.x, fmaf(-a.y, b.y, c.x));
  c.y = fmaf(a.x, b.y, fmaf(a.y, b.x, c.y));
}

// In-place radix-2 FFT, 512 points, 256 threads per instance (lt in [0,256)).
// All threads of the block must call (barriers). inv=1 => conj twiddles (unnormalized IDFT).
__device__ inline void fft512_lds(float2* a, const float2* w, int lt, int inv) {
  #pragma unroll
  for (int s = 0; s < 2; ++s) {
    int i = lt + (s << 8);
    int j = (int)(__brev((unsigned)i) >> 23);
    if (j > i) { float2 t = a[i]; a[i] = a[j]; a[j] = t; }
  }
  __syncthreads();
  for (int s = 1; s <= 9; ++s) {
    int half = 1 << (s - 1);
    int pos = lt & (half - 1);
    int grp = lt >> (s - 1);
    int i = (grp << s) + pos;
    int j = i + half;
    float2 tw = w[pos << (9 - s)];
    if (inv) tw.y = -tw.y;
    float2 t = cmul(a[j], tw);
    float2 ai = a[i];
    a[j] = make_float2(ai.x - t.x, ai.y - t.y);
    a[i] = make_float2(ai.x + t.x, ai.y + t.y);
    __syncthreads();
  }
}

// Bluestein core: buf must be filled (512, zero-padded); leaves conv result in buf.
// Bt: global pointwise table (prescaled by 1/512).
__device__ inline void bluestein_core(float2* buf, const float2* w512s, const float2* __restrict__ Bt, int lt) {
  __syncthreads();
  fft512_lds(buf, w512s, lt, 0);
  #pragma unroll
  for (int s = 0; s < 2; ++s) { int i = lt + (s << 8); buf[i] = cmul(buf[i], Bt[i]); }
  __syncthreads();
  fft512_lds(buf, w512s, lt, 1);
}

// Three fused 390-point DFTs (shared index math / twiddles). 390 = 30 x 13.
// Thread tid<390 returns X_r[tid]. INV=1 => e^{+2pi i nk/390} (unnormalized inverse).
template <int INV>
__device__ inline void dft390x3(const float2* a0, const float2* a1, const float2* a2,
                                float2* b0, float2* b1, float2* b2,
                                const float2* w, int tid,
                                float2& X0, float2& X1, float2& X2) {
  bool act = tid < 390;
  if (act) {
    int ka = tid % 30, nb = tid / 30;
    float2 c0 = make_float2(0.f, 0.f), c1 = c0, c2 = c0;
    int idx = 0, step = 13 * ka;  // < 390
    #pragma unroll 6
    for (int na = 0; na < 30; ++na) {
      float2 tw = w[idx];
      if (INV) tw.y = -tw.y;
      int src = 13 * na + nb;
      cfma(c0, a0[src], tw);
      cfma(c1, a1[src], tw);
      cfma(c2, a2[src], tw);
      idx += step; if (idx >= 390) idx -= 390;
    }
    float2 t2 = w[nb * ka];  // nb*ka <= 348
    if (INV) t2.y = -t2.y;
    int o = ka * 13 + nb;
    b0[o] = cmul(c0, t2);
    b1[o] = cmul(c1, t2);
    b2[o] = cmul(c2, t2);
  }
  __syncthreads();
  if (act) {
    int ka = tid % 30, kb = tid / 30;
    float2 c0 = make_float2(0.f, 0.f), c1 = c0, c2 = c0;
    int idx = 0, step = 30 * kb;  // < 390
    #pragma unroll
    for (int nb = 0; nb < 13; ++nb) {
      float2 tw = w[idx];
      if (INV) tw.y = -tw.y;
      int src = ka * 13 + nb;
      cfma(c0, b0[src], tw);
      cfma(c1, b1[src], tw);
      cfma(c2, b2[src], tw);
      idx += step; if (idx >= 390) idx -= 390;
    }
    X0 = c0; X1 = c1; X2 = c2;
  }
  __syncthreads();
}

// ---------------- kernels ----------------

__global__ __launch_bounds__(512) void k_init(float2* __restrict__ ws, float* __restrict__ out) {
  int tid = threadIdx.x;
  __shared__ float2 bufE[512], bufO[512];
  __shared__ float2 w512s[512];
  __shared__ float2 chirps[211];
  const double PI = 3.14159265358979323846;
  for (int j = tid; j < 390; j += 512) {
    double a = -2.0 * PI * (double)j / 390.0; double s, c; sincos(a, &s, &c);
    ws[OFF_W390 + j] = make_float2((float)c, (float)s);
  }
  for (int j = tid; j < 780; j += 512) {
    double a = 2.0 * PI * (double)j / 1170.0; double s, c; sincos(a, &s, &c);
    ws[OFF_T1170 + j] = make_float2((float)c, (float)s);
  }
  for (int j = tid; j < 512; j += 512) {
    double a = -2.0 * PI * (double)j / 512.0; double s, c; sincos(a, &s, &c);
    float2 v = make_float2((float)c, (float)s);
    ws[OFF_W512 + j] = v; w512s[j] = v;
  }
  for (int n = tid; n < 211; n += 512) {
    int m = (n * n) % 422;
    double a = PI * (double)m / 211.0; double s, c; sincos(a, &s, &c);
    float2 v = make_float2((float)c, (float)s);
    ws[OFF_CHIRP + n] = v; chirps[n] = v;
  }
  for (int p = tid; p < 211; p += 512) {
    double a = 2.0 * PI * (double)p / 422.0; double s, c; sincos(a, &s, &c);
    ws[OFF_U422 + p] = make_float2((float)c, (float)s);
  }
  if (tid < NF) out[tid] = 0.0f;
  __syncthreads();
  // group 0 builds b~ -> Bf ; group 1 builds conj(b~) -> Bi (simultaneously)
  int g = tid >> 8, lt = tid & 255;
  float2* buf = g ? bufO : bufE;
  #pragma unroll
  for (int s = 0; s < 2; ++s) {
    int i = lt + (s << 8);
    float2 v = make_float2(0.f, 0.f);
    if (i < 211) v = chirps[i];
    else if (i >= 302) v = chirps[512 - i];
    if (g) v.y = -v.y;
    buf[i] = v;
  }
  __syncthreads();
  fft512_lds(buf, w512s, lt, 0);
  const float sc = 1.0f / 512.0f;
  #pragma unroll
  for (int s = 0; s < 2; ++s) {
    int i = lt + (s << 8);
    float2 v = buf[i];
    v.x *= sc; v.y *= sc;
    ws[(g ? OFF_BI : OFF_BF) + i] = v;
  }
}

// A1: rows of padded x -> length-1170 forward DFT via 3x pre-twiddled DFT-390.
__global__ __launch_bounds__(448) void k_rowfft(const float* __restrict__ x, float2* __restrict__ ws) {
  int i = blockIdx.x;  // < 211
  int tid = threadIdx.x;
  __shared__ float2 a0[390], a1[390], a2[390], b0[390], b1[390], b2[390];
  __shared__ float2 w390s[390];
  __shared__ float2 t1170s[780];
  for (int j = tid; j < 390; j += 448) w390s[j] = ws[OFF_W390 + j];
  for (int j = tid; j < 780; j += 448) t1170s[j] = ws[OFF_T1170 + j];
  __syncthreads();
  for (int j = tid; j < 390; j += 448) {
    float xv = 100.0f * x[i * 390 + j];
    a0[j] = make_float2(xv, 0.0f);
    float2 t1 = t1170s[j];        // need e^{-2pi i r j/1170} = conj(t1170[r j])
    a1[j] = make_float2(xv * t1.x, -xv * t1.y);
    float2 t2 = t1170s[2 * j];
    a2[j] = make_float2(xv * t2.x, -xv * t2.y);
  }
  __syncthreads();
  float2 X0 = make_float2(0,0), X1 = X0, X2 = X0;
  dft390x3<0>(a0, a1, a2, b0, b1, b2, w390s, tid, X0, X1, X2);
  if (tid < 390) {
    float2* X = ws + OFF_X;
    size_t base = (size_t)i * D2 + 3 * (size_t)tid;
    X[base + 0] = X0; X[base + 1] = X1; X[base + 2] = X2;  // X[3m+r]
  }
}

// A2: columns (8 per block) length-422 forward DFT from 211-support rows, via 2x Bluestein-211. In-place in X.
__global__ __launch_bounds__(512) void k_colfft(float2* __restrict__ ws) {
  int tid = threadIdx.x;
  int q0 = blockIdx.x * 8;
  int ncols = min(8, D2 - q0);
  __shared__ float Xre[8][212], Xim[8][212];
  __shared__ float2 bufE[512], bufO[512];
  __shared__ float2 w512s[512], chirps[211], u422s[211];
  for (int j = tid; j < 512; j += 512) w512s[j] = ws[OFF_W512 + j];
  for (int j = tid; j < 211; j += 512) { chirps[j] = ws[OFF_CHIRP + j]; u422s[j] = ws[OFF_U422 + j]; }
  float2* X = ws + OFF_X;
  const float2* Bf = ws + OFF_BF;
  for (int idx = tid; idx < 211 * 8; idx += 512) {
    int i = idx >> 3, c = idx & 7;
    float2 v = make_float2(0.f, 0.f);
    if (c < ncols) v = X[(size_t)i * D2 + q0 + c];
    Xre[c][i] = v.x; Xim[c][i] = v.y;
  }
  __syncthreads();
  int g = tid >> 8, lt = tid & 255;
  float2* buf = g ? bufO : bufE;
  for (int c = 0; c < ncols; ++c) {
    #pragma unroll
    for (int s = 0; s < 2; ++s) {
      int i2 = lt + (s << 8);
      float2 v = make_float2(0.f, 0.f);
      if (i2 < 211) {
        v = make_float2(Xre[c][i2], Xim[c][i2]);
        if (g) v = cmulc(v, u422s[i2]);   // odd outputs: pre-twiddle e^{-2pi i n/422}
        v = cmulc(v, chirps[i2]);         // forward pre-chirp: * conj(W)
      }
      buf[i2] = v;
    }
    bluestein_core(buf, w512s, Bf, lt);
    #pragma unroll
    for (int s = 0; s < 2; ++s) {
      int i2 = lt + (s << 8);
      if (i2 < 211) {
        float2 r = cmulc(buf[i2], chirps[i2]);  // forward post-chirp: * conj(W)
        X[(size_t)(2 * i2 + g) * D2 + q0 + c] = r;
      }
    }
    __syncthreads();
  }
}

// Stage 1: per (filter, k1): Y = X row * H row; inverse time transform via 3x IDFT-390 + combine; write Z.
__global__ __launch_bounds__(448) void k_stage1(const float* __restrict__ Hr, const float* __restrict__ Hi,
                                                float2* __restrict__ ws, int f0) {
  int k1 = blockIdx.x;
  int fl = blockIdx.y;
  int f = f0 + fl;
  int tid = threadIdx.x;
  __shared__ float2 a0[390], a1[390], a2[390], b0[390], b1[390], b2[390];
  __shared__ float2 w390s[390];
  __shared__ float2 t1170s[780];
  for (int j = tid; j < 390; j += 448) w390s[j] = ws[OFF_W390 + j];
  for (int j = tid; j < 780; j += 448) t1170s[j] = ws[OFF_T1170 + j];
  const float2* X = ws + OFF_X + (size_t)k1 * D2;
  size_t hbase = (size_t)f * (D1 * D2) + (size_t)k1 * D2;
  for (int k2 = tid; k2 < D2; k2 += 448) {
    float2 xv = X[k2];
    float2 h = make_float2(Hr[hbase + k2], Hi[hbase + k2]);
    float2 y = cmul(xv, h);
    int r = k2 % 3, m = k2 / 3;
    (r == 0 ? a0 : (r == 1 ? a1 : a2))[m] = y;
  }
  __syncthreads();
  float2 A0 = make_float2(0,0), A1 = A0, A2 = A0;
  dft390x3<1>(a0, a1, a2, b0, b1, b2, w390s, tid, A0, A1, A2);
  if (tid < 390) {
    int q = tid;
    float2 t1 = t1170s[q], t2 = t1170s[2 * q];
    float2 m1 = cmul(t1, A1), m2 = cmul(t2, A2);
    float2 z = make_float2(A0.x + m1.x + m2.x, A0.y + m1.y + m2.y);
    float2* Zg = ws + OFF_Z;
    Zg[((size_t)fl * D1 + k1) * ZSTRIDE + q] = z;
  }
}

// Stage 2: per (filter, 8 columns): inverse freq transform (2x Bluestein IDFT-211), real part, square, reduce.
__global__ __launch_bounds__(512) void k_stage2(float2* __restrict__ ws, float* __restrict__ out, int f0) {
  int fl = blockIdx.y;
  int f = f0 + fl;
  int q0 = blockIdx.x * 8;
  int ncols = min(8, Q2 - q0);
  int tid = threadIdx.x;
  __shared__ float Ze_re[8][212], Ze_im[8][212], Zo_re[8][212], Zo_im[8][212];
  __shared__ float2 bufE[512], bufO[512];
  __shared__ float2 w512s[512], chirps[211], u422s[211];
  __shared__ float wredu[8];
  for (int j = tid; j < 512; j += 512) w512s[j] = ws[OFF_W512 + j];
  for (int j = tid; j < 211; j += 512) { chirps[j] = ws[OFF_CHIRP + j]; u422s[j] = ws[OFF_U422 + j]; }
  const float2* Zg = ws + OFF_Z + (size_t)fl * D1 * ZSTRIDE;
  const float2* Bi = ws + OFF_BI;
  for (int idx = tid; idx < D1 * 8; idx += 512) {
    int k1 = idx >> 3, c = idx & 7;
    float2 v = make_float2(0.f, 0.f);
    if (c < ncols) v = Zg[(size_t)k1 * ZSTRIDE + q0 + c];
    int h = k1 >> 1;
    if (k1 & 1) { Zo_re[c][h] = v.x; Zo_im[c][h] = v.y; }
    else        { Ze_re[c][h] = v.x; Ze_im[c][h] = v.y; }
  }
  __syncthreads();
  int g = tid >> 8, lt = tid & 255;
  float2* buf = g ? bufO : bufE;
  float acc = 0.0f;
  for (int c = 0; c < ncols; ++c) {
    #pragma unroll
    for (int s = 0; s < 2; ++s) {
      int i2 = lt + (s << 8);
      float2 v = make_float2(0.f, 0.f);
      if (i2 < 211) {
        float2 zz = g ? make_float2(Zo_re[c][i2], Zo_im[c][i2])
                      : make_float2(Ze_re[c][i2], Ze_im[c][i2]);
        v = cmul(zz, chirps[i2]);  // inverse pre-chirp: * W
      }
      buf[i2] = v;
    }
    bluestein_core(buf, w512s, Bi, lt);
    #pragma unroll
    for (int s = 0; s < 2; ++s) {
      int i2 = lt + (s << 8);
      if (i2 < 211) buf[i2] = cmul(buf[i2], chirps[i2]);  // inverse post-chirp: * W
    }
    __syncthreads();
    if (tid < 211) {
      float2 E = bufE[tid], O = bufO[tid];
      float2 u = u422s[tid];
      float yre = E.x + u.x * O.x - u.y * O.y;  // Re(E + u*O)
      float v = yre * SNORM;
      acc += fmaxf(v * v, 1e-8f);
    }
    __syncthreads();
  }
  // block reduction (8 waves)
  for (int off = 32; off > 0; off >>= 1) acc += __shfl_down(acc, off, 64);
  int wid = tid >> 6, lane = tid & 63;
  if (lane == 0) wredu[wid] = acc;
  __syncthreads();
  if (tid == 0) {
    float tot = 0.f;
    #pragma unroll
    for (int wdx = 0; wdx < 8; ++wdx) tot += wredu[wdx];
    atomicAdd(&out[f], tot * OUTSCALE);
  }
}

extern "C" void kernel_launch(void* const* d_in, const int* in_sizes, int n_in,
                              void* d_out, int out_size, void* d_ws, size_t ws_size,
                              hipStream_t stream) {
  const float* x  = (const float*)d_in[0];
  const float* Hr = (const float*)d_in[1];
  const float* Hi = (const float*)d_in[2];
  float* out = (float*)d_out;
  float2* ws = (float2*)d_ws;

  long long avail = (long long)ws_size - (long long)OFF_Z * (long long)sizeof(float2);
  long long zper = (long long)D1 * ZSTRIDE * (long long)sizeof(float2);  // 1,323,392 B per filter
  int chunk = (avail > 0) ? (int)(avail / zper) : 1;
  if (chunk < 1) chunk = 1;
  if (chunk > NF) chunk = NF;

  k_init<<<dim3(1), dim3(512), 0, stream>>>(ws, out);
  k_rowfft<<<dim3(211), dim3(448), 0, stream>>>(x, ws);
  k_colfft<<<dim3(147), dim3(512), 0, stream>>>(ws);  // ceil(1170/8)
  for (int f0 = 0; f0 < NF; f0 += chunk) {
    int nf = NF - f0;
    if (nf > chunk) nf = chunk;
    k_stage1<<<dim3(422, nf), dim3(448), 0, stream>>>(Hr, Hi, ws, f0);
    k_stage2<<<dim3(49, nf), dim3(512), 0, stream>>>(ws, out, f0);  // ceil(390/8)
  }
}

// Round 2
// 858.685 us; speedup vs baseline: 1.7276x; 1.7276x over previous
//
#include <hip/hip_runtime.h>
#include <math.h>

// Problem constants
constexpr int NF  = 119;   // filters
constexpr int D1  = 422;   // padded freq
constexpr int D2  = 1170;  // padded time
constexpr float SNORM    = 2.0253575e-06f;    // 1/(422*1170)
constexpr float OUTSCALE = 1.2152144e-05f;    // 1/(211*390)

// ws layout. float2-unit offsets for tables/X; float-unit for WMAT/Z.
constexpr int OFF_W390  = 0;        // 390
constexpr int OFF_T1170 = 390;      // 780 : e^{+2pi i j/1170}, j<780
constexpr int OFF_W512  = 1170;     // 512 : e^{-2pi i j/512}
constexpr int OFF_CHIRP = 1682;     // 211 : W[n]=e^{+i pi n^2/211}
constexpr int OFF_U422  = 1893;     // 211 : e^{+2pi i p/422}
constexpr int OFF_BF    = 2104;     // 512 : FFT512(bwrap)/512
constexpr int OFF_BI    = 2616;     // 512 : (unused now, kept for layout stability)
// floats:
constexpr int WMAT_F    = 6272;     // 424 x 256 floats (A matrix, [k][p], stride 256)
constexpr int X_F2      = 57408;    // float2 index of X (422*1170 float2)
constexpr long long Z_F = 1102304;  // float offset of Z planes
constexpr int ZSTR      = 448;      // Z row stride (floats)
constexpr long long ZPF = 424LL * ZSTR;  // floats per filter (189952)

__device__ inline float2 cmul(float2 a, float2 b) {
  return make_float2(fmaf(a.x, b.x, -(a.y * b.y)), fmaf(a.x, b.y, a.y * b.x));
}
__device__ inline float2 cmulc(float2 a, float2 b) {  // a * conj(b)
  return make_float2(fmaf(a.x, b.x, (a.y * b.y)), fmaf(a.y, b.x, -(a.x * b.y)));
}
__device__ inline void cfma(float2& c, float2 a, float2 b) {
  c.x = fmaf(a.x, b.x, fmaf(-a.y, b.y, c.x));
  c.y = fmaf(a.x, b.y, fmaf(a.y, b.x, c.y));
}

// In-place radix-2 FFT, 512 points, 256 threads per instance (lt in [0,256)).
__device__ inline void fft512_lds(float2* a, const float2* w, int lt, int inv) {
  #pragma unroll
  for (int s = 0; s < 2; ++s) {
    int i = lt + (s << 8);
    int j = (int)(__brev((unsigned)i) >> 23);
    if (j > i) { float2 t = a[i]; a[i] = a[j]; a[j] = t; }
  }
  __syncthreads();
  for (int s = 1; s <= 9; ++s) {
    int half = 1 << (s - 1);
    int pos = lt & (half - 1);
    int grp = lt >> (s - 1);
    int i = (grp << s) + pos;
    int j = i + half;
    float2 tw = w[pos << (9 - s)];
    if (inv) tw.y = -tw.y;
    float2 t = cmul(a[j], tw);
    float2 ai = a[i];
    a[j] = make_float2(ai.x - t.x, ai.y - t.y);
    a[i] = make_float2(ai.x + t.x, ai.y + t.y);
    __syncthreads();
  }
}

__device__ inline void bluestein_core(float2* buf, const float2* w512s, const float2* __restrict__ Bt, int lt) {
  __syncthreads();
  fft512_lds(buf, w512s, lt, 0);
  #pragma unroll
  for (int s = 0; s < 2; ++s) { int i = lt + (s << 8); buf[i] = cmul(buf[i], Bt[i]); }
  __syncthreads();
  fft512_lds(buf, w512s, lt, 1);
}

// Three fused 390-point DFTs. 390 = 30 x 13. INV=1 => e^{+2pi i nk/390}.
template <int INV>
__device__ inline void dft390x3(const float2* a0, const float2* a1, const float2* a2,
                                float2* b0, float2* b1, float2* b2,
                                const float2* w, int tid,
                                float2& X0, float2& X1, float2& X2) {
  bool act = tid < 390;
  if (act) {
    int ka = tid % 30, nb = tid / 30;
    float2 c0 = make_float2(0.f, 0.f), c1 = c0, c2 = c0;
    int idx = 0, step = 13 * ka;
    #pragma unroll 6
    for (int na = 0; na < 30; ++na) {
      float2 tw = w[idx];
      if (INV) tw.y = -tw.y;
      int src = 13 * na + nb;
      cfma(c0, a0[src], tw);
      cfma(c1, a1[src], tw);
      cfma(c2, a2[src], tw);
      idx += step; if (idx >= 390) idx -= 390;
    }
    float2 t2 = w[nb * ka];
    if (INV) t2.y = -t2.y;
    int o = ka * 13 + nb;
    b0[o] = cmul(c0, t2);
    b1[o] = cmul(c1, t2);
    b2[o] = cmul(c2, t2);
  }
  __syncthreads();
  if (act) {
    int ka = tid % 30, kb = tid / 30;
    float2 c0 = make_float2(0.f, 0.f), c1 = c0, c2 = c0;
    int idx = 0, step = 30 * kb;
    #pragma unroll
    for (int nb = 0; nb < 13; ++nb) {
      float2 tw = w[idx];
      if (INV) tw.y = -tw.y;
      int src = ka * 13 + nb;
      cfma(c0, b0[src], tw);
      cfma(c1, b1[src], tw);
      cfma(c2, b2[src], tw);
      idx += step; if (idx >= 390) idx -= 390;
    }
    X0 = c0; X1 = c1; X2 = c2;
  }
  __syncthreads();
}

// ---------------- kernels ----------------

__global__ __launch_bounds__(512) void k_init(float2* __restrict__ ws, float* __restrict__ out) {
  int tid = threadIdx.x;
  __shared__ float2 bufE[512], bufO[512];
  __shared__ float2 w512s[512];
  __shared__ float2 chirps[211];
  const double PI = 3.14159265358979323846;
  for (int j = tid; j < 390; j += 512) {
    double a = -2.0 * PI * (double)j / 390.0; double s, c; sincos(a, &s, &c);
    ws[OFF_W390 + j] = make_float2((float)c, (float)s);
  }
  for (int j = tid; j < 780; j += 512) {
    double a = 2.0 * PI * (double)j / 1170.0; double s, c; sincos(a, &s, &c);
    ws[OFF_T1170 + j] = make_float2((float)c, (float)s);
  }
  for (int j = tid; j < 512; j += 512) {
    double a = -2.0 * PI * (double)j / 512.0; double s, c; sincos(a, &s, &c);
    float2 v = make_float2((float)c, (float)s);
    ws[OFF_W512 + j] = v; w512s[j] = v;
  }
  for (int n = tid; n < 211; n += 512) {
    int m = (n * n) % 422;
    double a = PI * (double)m / 211.0; double s, c; sincos(a, &s, &c);
    float2 v = make_float2((float)c, (float)s);
    ws[OFF_CHIRP + n] = v; chirps[n] = v;
  }
  for (int p = tid; p < 211; p += 512) {
    double a = 2.0 * PI * (double)p / 422.0; double s, c; sincos(a, &s, &c);
    ws[OFF_U422 + p] = make_float2((float)c, (float)s);
  }
  if (tid < NF) out[tid] = 0.0f;
  __syncthreads();
  // group 0 builds b~ -> Bf ; group 1 runs the same shape (output unused) to keep barriers uniform
  int g = tid >> 8, lt = tid & 255;
  float2* buf = g ? bufO : bufE;
  #pragma unroll
  for (int s = 0; s < 2; ++s) {
    int i = lt + (s << 8);
    float2 v = make_float2(0.f, 0.f);
    if (i < 211) v = chirps[i];
    else if (i >= 302) v = chirps[512 - i];
    buf[i] = v;
  }
  __syncthreads();
  fft512_lds(buf, w512s, lt, 0);
  const float sc = 1.0f / 512.0f;
  if (g == 0) {
    #pragma unroll
    for (int s = 0; s < 2; ++s) {
      int i = lt + (s << 8);
      float2 v = buf[i];
      v.x *= sc; v.y *= sc;
      ws[OFF_BF + i] = v;
    }
  }
}

// Build A matrix for the stage2 GEMM: A[k][p], k=2*k1(+1), stride 256.
// A[2k1][p] = c*SNORM*cos(2pi k1 p/422); A[2k1+1][p] = -c*SNORM*sin(...)
__global__ __launch_bounds__(256) void k_initw(float* __restrict__ wsf) {
  int k = blockIdx.x;       // [0,424)
  int p = threadIdx.x;      // [0,256)
  int k1 = k >> 1;
  float v = 0.f;
  if (p < 211) {
    int m = (p * k1) % 422;
    double a = 2.0 * 3.14159265358979323846 * (double)m / 422.0;
    double s, c; sincos(a, &s, &c);
    float cf = (k1 == 0 || k1 == 211) ? 1.f : 2.f;
    v = ((k & 1) ? -(float)s : (float)c) * cf * SNORM;
  }
  wsf[WMAT_F + k * 256 + p] = v;
}

// A1: rows of padded x -> length-1170 forward DFT via 3x pre-twiddled DFT-390.
__global__ __launch_bounds__(448) void k_rowfft(const float* __restrict__ x, float* __restrict__ wsf) {
  int i = blockIdx.x;  // < 211
  int tid = threadIdx.x;
  float2* ws = (float2*)wsf;
  __shared__ float2 a0[390], a1[390], a2[390], b0[390], b1[390], b2[390];
  __shared__ float2 w390s[390];
  __shared__ float2 t1170s[780];
  for (int j = tid; j < 390; j += 448) w390s[j] = ws[OFF_W390 + j];
  for (int j = tid; j < 780; j += 448) t1170s[j] = ws[OFF_T1170 + j];
  __syncthreads();
  for (int j = tid; j < 390; j += 448) {
    float xv = 100.0f * x[i * 390 + j];
    a0[j] = make_float2(xv, 0.0f);
    float2 t1 = t1170s[j];
    a1[j] = make_float2(xv * t1.x, -xv * t1.y);
    float2 t2 = t1170s[2 * j];
    a2[j] = make_float2(xv * t2.x, -xv * t2.y);
  }
  __syncthreads();
  float2 X0 = make_float2(0,0), X1 = X0, X2 = X0;
  dft390x3<0>(a0, a1, a2, b0, b1, b2, w390s, tid, X0, X1, X2);
  if (tid < 390) {
    float2* X = ws + X_F2;
    size_t base = (size_t)i * D2 + 3 * (size_t)tid;
    X[base + 0] = X0; X[base + 1] = X1; X[base + 2] = X2;
  }
}

// A2: columns (8 per block) length-422 forward DFT via 2x Bluestein-211. In-place in X.
__global__ __launch_bounds__(512) void k_colfft(float* __restrict__ wsf) {
  int tid = threadIdx.x;
  int q0 = blockIdx.x * 8;
  int ncols = min(8, D2 - q0);
  float2* ws = (float2*)wsf;
  __shared__ float Xre[8][212], Xim[8][212];
  __shared__ float2 bufE[512], bufO[512];
  __shared__ float2 w512s[512], chirps[211], u422s[211];
  for (int j = tid; j < 512; j += 512) w512s[j] = ws[OFF_W512 + j];
  for (int j = tid; j < 211; j += 512) { chirps[j] = ws[OFF_CHIRP + j]; u422s[j] = ws[OFF_U422 + j]; }
  float2* X = ws + X_F2;
  const float2* Bf = ws + OFF_BF;
  for (int idx = tid; idx < 211 * 8; idx += 512) {
    int i = idx >> 3, c = idx & 7;
    float2 v = make_float2(0.f, 0.f);
    if (c < ncols) v = X[(size_t)i * D2 + q0 + c];
    Xre[c][i] = v.x; Xim[c][i] = v.y;
  }
  __syncthreads();
  int g = tid >> 8, lt = tid & 255;
  float2* buf = g ? bufO : bufE;
  for (int c = 0; c < ncols; ++c) {
    #pragma unroll
    for (int s = 0; s < 2; ++s) {
      int i2 = lt + (s << 8);
      float2 v = make_float2(0.f, 0.f);
      if (i2 < 211) {
        v = make_float2(Xre[c][i2], Xim[c][i2]);
        if (g) v = cmulc(v, u422s[i2]);
        v = cmulc(v, chirps[i2]);
      }
      buf[i2] = v;
    }
    bluestein_core(buf, w512s, Bf, lt);
    #pragma unroll
    for (int s = 0; s < 2; ++s) {
      int i2 = lt + (s << 8);
      if (i2 < 211) {
        float2 r = cmulc(buf[i2], chirps[i2]);
        X[(size_t)(2 * i2 + g) * D2 + q0 + c] = r;
      }
    }
    __syncthreads();
  }
}

// Stage 1 (Hermitian-halved): rows k1 in [0,211]. Ytilde = X * G, G = (H[k1,k2]+conj(H[-k1,-k2]))/2.
// Inverse time transform (3x IDFT-390 + twiddle combine) -> Z rows 2*k1 (re), 2*k1+1 (im).
__global__ __launch_bounds__(448) void k_stage1(const float* __restrict__ Hr, const float* __restrict__ Hi,
                                                float* __restrict__ wsf, int f0) {
  int k1 = blockIdx.x;   // [0,212)
  int fl = blockIdx.y;
  int f = f0 + fl;
  int tid = threadIdx.x;
  float2* ws = (float2*)wsf;
  __shared__ float2 a0[390], a1[390], a2[390], b0[390], b1[390], b2[390];
  __shared__ float2 w390s[390];
  __shared__ float2 t1170s[780];
  for (int j = tid; j < 390; j += 448) w390s[j] = ws[OFF_W390 + j];
  for (int j = tid; j < 780; j += 448) t1170s[j] = ws[OFF_T1170 + j];
  const float2* X = ws + X_F2 + (size_t)k1 * D2;
  int m1 = (422 - k1) % 422;
  size_t hb  = (size_t)f * (D1 * D2) + (size_t)k1 * D2;
  size_t hmb = (size_t)f * (D1 * D2) + (size_t)m1 * D2;
  for (int k2 = tid; k2 < D2; k2 += 448) {
    float2 xv = X[k2];
    int rk = (k2 == 0) ? 0 : (D2 - k2);
    float gr = 0.5f * (Hr[hb + k2] + Hr[hmb + rk]);
    float gi = 0.5f * (Hi[hb + k2] - Hi[hmb + rk]);
    float2 y = make_float2(fmaf(xv.x, gr, -(xv.y * gi)), fmaf(xv.x, gi, xv.y * gr));
    int r = k2 % 3, m = k2 / 3;
    (r == 0 ? a0 : (r == 1 ? a1 : a2))[m] = y;
  }
  __syncthreads();
  float2 A0 = make_float2(0,0), A1 = A0, A2 = A0;
  dft390x3<1>(a0, a1, a2, b0, b1, b2, w390s, tid, A0, A1, A2);
  if (tid < 390) {
    int q = tid;
    float2 t1 = t1170s[q], t2 = t1170s[2 * q];
    float zr = A0.x + (t1.x * A1.x - t1.y * A1.y) + (t2.x * A2.x - t2.y * A2.y);
    float zi = A0.y + (t1.x * A1.y + t1.y * A1.x) + (t2.x * A2.y + t2.y * A2.x);
    float* Z = wsf + Z_F + (size_t)fl * ZPF + (size_t)(2 * k1) * ZSTR;
    Z[q] = zr;
    Z[ZSTR + q] = zi;
  }
}

// Stage 2: per-filter fused GEMM y[211x390] = A[424x211]^T-style dot over k, + square/clamp/mean epilogue.
// Block: 256 threads, 64x64 tile, 4x4 micro-tile. Grid: (4 Mtiles * 7 Ntiles, nf).
__global__ __launch_bounds__(256) void k_gemm(const float* __restrict__ wsf, float* __restrict__ out, int f0) {
  int fl = blockIdx.y;
  int f = f0 + fl;
  int mt = blockIdx.x / 7, nt = blockIdx.x % 7;
  int tid = threadIdx.x;
  int pbase = mt * 64, qbase = nt * 64;
  __shared__ float As[8][64];
  __shared__ float Bs[8][64];
  const float* A = wsf + WMAT_F;
  const float* B = wsf + Z_F + (size_t)fl * ZPF;
  int kk = tid >> 5, cc = (tid & 31) << 1;
  int ty = tid >> 4, tx = tid & 15;
  float C[4][4] = {};
  for (int k0 = 0; k0 < 424; k0 += 8) {
    float2 av = *(const float2*)(A + (size_t)(k0 + kk) * 256 + pbase + cc);
    float2 bv = *(const float2*)(B + (size_t)(k0 + kk) * ZSTR + qbase + cc);
    __syncthreads();
    *(float2*)&As[kk][cc] = av;
    *(float2*)&Bs[kk][cc] = bv;
    __syncthreads();
    #pragma unroll
    for (int kq = 0; kq < 8; ++kq) {
      float4 a4 = *(const float4*)&As[kq][ty << 2];
      float4 b4 = *(const float4*)&Bs[kq][tx << 2];
      C[0][0] = fmaf(a4.x, b4.x, C[0][0]); C[0][1] = fmaf(a4.x, b4.y, C[0][1]);
      C[0][2] = fmaf(a4.x, b4.z, C[0][2]); C[0][3] = fmaf(a4.x, b4.w, C[0][3]);
      C[1][0] = fmaf(a4.y, b4.x, C[1][0]); C[1][1] = fmaf(a4.y, b4.y, C[1][1]);
      C[1][2] = fmaf(a4.y, b4.z, C[1][2]); C[1][3] = fmaf(a4.y, b4.w, C[1][3]);
      C[2][0] = fmaf(a4.z, b4.x, C[2][0]); C[2][1] = fmaf(a4.z, b4.y, C[2][1]);
      C[2][2] = fmaf(a4.z, b4.z, C[2][2]); C[2][3] = fmaf(a4.z, b4.w, C[2][3]);
      C[3][0] = fmaf(a4.w, b4.x, C[3][0]); C[3][1] = fmaf(a4.w, b4.y, C[3][1]);
      C[3][2] = fmaf(a4.w, b4.z, C[3][2]); C[3][3] = fmaf(a4.w, b4.w, C[3][3]);
    }
  }
  float acc = 0.f;
  #pragma unroll
  for (int i = 0; i < 4; ++i) {
    int p = pbase + (ty << 2) + i;
    #pragma unroll
    for (int j = 0; j < 4; ++j) {
      int q = qbase + (tx << 2) + j;
      if (p < 211 && q < 390) acc += fmaxf(C[i][j] * C[i][j], 1e-8f);
    }
  }
  for (int off = 32; off > 0; off >>= 1) acc += __shfl_down(acc, off, 64);
  __shared__ float wred[4];
  int wid = tid >> 6, lane = tid & 63;
  if (lane == 0) wred[wid] = acc;
  __syncthreads();
  if (tid == 0) {
    float tot = wred[0] + wred[1] + wred[2] + wred[3];
    atomicAdd(&out[f], tot * OUTSCALE);
  }
}

extern "C" void kernel_launch(void* const* d_in, const int* in_sizes, int n_in,
                              void* d_out, int out_size, void* d_ws, size_t ws_size,
                              hipStream_t stream) {
  const float* x  = (const float*)d_in[0];
  const float* Hr = (const float*)d_in[1];
  const float* Hi = (const float*)d_in[2];
  float* out = (float*)d_out;
  float* wsf = (float*)d_ws;

  long long availf = (long long)(ws_size / 4) - Z_F;
  int chunk = (availf > 0) ? (int)(availf / ZPF) : 1;
  if (chunk < 1) chunk = 1;
  if (chunk > NF) chunk = NF;

  k_init<<<dim3(1), dim3(512), 0, stream>>>((float2*)d_ws, out);
  k_initw<<<dim3(424), dim3(256), 0, stream>>>(wsf);
  k_rowfft<<<dim3(211), dim3(448), 0, stream>>>(x, wsf);
  k_colfft<<<dim3(147), dim3(512), 0, stream>>>(wsf);
  for (int f0 = 0; f0 < NF; f0 += chunk) {
    int nf = NF - f0;
    if (nf > chunk) nf = chunk;
    k_stage1<<<dim3(212, nf), dim3(448), 0, stream>>>(Hr, Hi, wsf, f0);
    k_gemm<<<dim3(28, nf), dim3(256), 0, stream>>>(wsf, out, f0);
  }
}

// Round 3
// 779.831 us; speedup vs baseline: 1.9023x; 1.1011x over previous
//
#include <hip/hip_runtime.h>
#include <math.h>

// Problem constants
constexpr int NF  = 119;
constexpr int D1  = 422;
constexpr int D2  = 1170;

// Table offsets (float2 units) inside the TAB region
constexpr int OFF_W390  = 0;        // 390 : e^{-2pi i j/390}
constexpr int OFF_T1170 = 390;      // 1170: e^{+2pi i j/1170}
constexpr int OFF_W512  = 1560;     // 512 : e^{-2pi i j/512}
constexpr int OFF_CHIRP = 2072;     // 211 : W[n]=e^{+i pi n^2/211}
constexpr int OFF_U422  = 2283;     // 211 : e^{+2pi i p/422}
constexpr int OFF_BF    = 2494;     // 512 : FFT512(bwrap)/512
constexpr int OFF_T422  = 3006;     // 422 : e^{+2pi i j/422}

// GEMM geometry
constexpr int KP1 = 2368;           // stage1 K (2*1170 padded to 74*32)
constexpr int KB1 = KP1 * 2;        // bytes per A/B1t row
constexpr int ZS2 = 784;            // Z' row stride (halves)
constexpr int KP2 = 448;            // stage2 K (2*212 padded to 14*32)
constexpr int KB2 = KP2 * 2;

// Scales: A = Y * 2^-10 ; stage2 A2 has no SNORM; y_true = y' * s, s = 1024/(422*1170)
constexpr float SC_A   = 9.765625e-4f;                 // 2^-10
constexpr double S_D   = 1024.0 / (422.0 * 1170.0);
constexpr float TH_CL  = (float)(1e-8 / (S_D * S_D));          // clamp in y'^2 domain
constexpr float FINAL  = (float)(S_D * S_D / (211.0 * 390.0)); // s^2 * OUTSCALE

typedef _Float16 h16;
typedef _Float16 h16x2 __attribute__((ext_vector_type(2)));
typedef _Float16 h16x8 __attribute__((ext_vector_type(8)));
typedef float f32x4 __attribute__((ext_vector_type(4)));

__device__ inline float2 cmul(float2 a, float2 b) {
  return make_float2(fmaf(a.x, b.x, -(a.y * b.y)), fmaf(a.x, b.y, a.y * b.x));
}
__device__ inline float2 cmulc(float2 a, float2 b) {  // a * conj(b)
  return make_float2(fmaf(a.x, b.x, (a.y * b.y)), fmaf(a.y, b.x, -(a.x * b.y)));
}
__device__ inline void cfma(float2& c, float2 a, float2 b) {
  c.x = fmaf(a.x, b.x, fmaf(-a.y, b.y, c.x));
  c.y = fmaf(a.x, b.y, fmaf(a.y, b.x, c.y));
}

__device__ inline void async16(const void* g, void* l) {
  __builtin_amdgcn_global_load_lds((const __attribute__((address_space(1))) unsigned int*)g,
                                   (__attribute__((address_space(3))) unsigned int*)l, 16, 0, 0);
}

// In-place radix-2 FFT, 512 points, 256 threads per instance.
__device__ inline void fft512_lds(float2* a, const float2* w, int lt, int inv) {
  #pragma unroll
  for (int s = 0; s < 2; ++s) {
    int i = lt + (s << 8);
    int j = (int)(__brev((unsigned)i) >> 23);
    if (j > i) { float2 t = a[i]; a[i] = a[j]; a[j] = t; }
  }
  __syncthreads();
  for (int s = 1; s <= 9; ++s) {
    int half = 1 << (s - 1);
    int pos = lt & (half - 1);
    int grp = lt >> (s - 1);
    int i = (grp << s) + pos;
    int j = i + half;
    float2 tw = w[pos << (9 - s)];
    if (inv) tw.y = -tw.y;
    float2 t = cmul(a[j], tw);
    float2 ai = a[i];
    a[j] = make_float2(ai.x - t.x, ai.y - t.y);
    a[i] = make_float2(ai.x + t.x, ai.y + t.y);
    __syncthreads();
  }
}

__device__ inline void bluestein_core(float2* buf, const float2* w512s, const float2* __restrict__ Bt, int lt) {
  __syncthreads();
  fft512_lds(buf, w512s, lt, 0);
  #pragma unroll
  for (int s = 0; s < 2; ++s) { int i = lt + (s << 8); buf[i] = cmul(buf[i], Bt[i]); }
  __syncthreads();
  fft512_lds(buf, w512s, lt, 1);
}

// Three fused 390-point DFTs. 390 = 30 x 13. INV=1 => e^{+2pi i nk/390}.
template <int INV>
__device__ inline void dft390x3(const float2* a0, const float2* a1, const float2* a2,
                                float2* b0, float2* b1, float2* b2,
                                const float2* w, int tid,
                                float2& X0, float2& X1, float2& X2) {
  bool act = tid < 390;
  if (act) {
    int ka = tid % 30, nb = tid / 30;
    float2 c0 = make_float2(0.f, 0.f), c1 = c0, c2 = c0;
    int idx = 0, step = 13 * ka;
    #pragma unroll 6
    for (int na = 0; na < 30; ++na) {
      float2 tw = w[idx];
      if (INV) tw.y = -tw.y;
      int src = 13 * na + nb;
      cfma(c0, a0[src], tw);
      cfma(c1, a1[src], tw);
      cfma(c2, a2[src], tw);
      idx += step; if (idx >= 390) idx -= 390;
    }
    float2 t2 = w[nb * ka];
    if (INV) t2.y = -t2.y;
    int o = ka * 13 + nb;
    b0[o] = cmul(c0, t2);
    b1[o] = cmul(c1, t2);
    b2[o] = cmul(c2, t2);
  }
  __syncthreads();
  if (act) {
    int ka = tid % 30, kb = tid / 30;
    float2 c0 = make_float2(0.f, 0.f), c1 = c0, c2 = c0;
    int idx = 0, step = 30 * kb;
    #pragma unroll
    for (int nb = 0; nb < 13; ++nb) {
      float2 tw = w[idx];
      if (INV) tw.y = -tw.y;
      int src = ka * 13 + nb;
      cfma(c0, b0[src], tw);
      cfma(c1, b1[src], tw);
      cfma(c2, b2[src], tw);
      idx += step; if (idx >= 390) idx -= 390;
    }
    X0 = c0; X1 = c1; X2 = c2;
  }
  __syncthreads();
}

// ---------------- kernels ----------------

__global__ __launch_bounds__(512) void k_init(float2* __restrict__ tab, float* __restrict__ out) {
  int tid = threadIdx.x;
  __shared__ float2 bufE[512], bufO[512];
  __shared__ float2 w512s[512];
  __shared__ float2 chirps[211];
  const double PI = 3.14159265358979323846;
  for (int j = tid; j < 390; j += 512) {
    double a = -2.0 * PI * (double)j / 390.0; double s, c; sincos(a, &s, &c);
    tab[OFF_W390 + j] = make_float2((float)c, (float)s);
  }
  for (int j = tid; j < 1170; j += 512) {
    double a = 2.0 * PI * (double)j / 1170.0; double s, c; sincos(a, &s, &c);
    tab[OFF_T1170 + j] = make_float2((float)c, (float)s);
  }
  for (int j = tid; j < 422; j += 512) {
    double a = 2.0 * PI * (double)j / 422.0; double s, c; sincos(a, &s, &c);
    tab[OFF_T422 + j] = make_float2((float)c, (float)s);
  }
  for (int j = tid; j < 512; j += 512) {
    double a = -2.0 * PI * (double)j / 512.0; double s, c; sincos(a, &s, &c);
    float2 v = make_float2((float)c, (float)s);
    tab[OFF_W512 + j] = v; w512s[j] = v;
  }
  for (int n = tid; n < 211; n += 512) {
    int m = (n * n) % 422;
    double a = PI * (double)m / 211.0; double s, c; sincos(a, &s, &c);
    float2 v = make_float2((float)c, (float)s);
    tab[OFF_CHIRP + n] = v; chirps[n] = v;
  }
  for (int p = tid; p < 211; p += 512) {
    double a = 2.0 * PI * (double)p / 422.0; double s, c; sincos(a, &s, &c);
    tab[OFF_U422 + p] = make_float2((float)c, (float)s);
  }
  if (tid < NF) out[tid] = 0.0f;
  __syncthreads();
  int g = tid >> 8, lt = tid & 255;
  float2* buf = g ? bufO : bufE;
  #pragma unroll
  for (int s = 0; s < 2; ++s) {
    int i = lt + (s << 8);
    float2 v = make_float2(0.f, 0.f);
    if (i < 211) v = chirps[i];
    else if (i >= 302) v = chirps[512 - i];
    buf[i] = v;
  }
  __syncthreads();
  fft512_lds(buf, w512s, lt, 0);
  const float sc = 1.0f / 512.0f;
  if (g == 0) {
    #pragma unroll
    for (int s = 0; s < 2; ++s) {
      int i = lt + (s << 8);
      float2 v = buf[i];
      v.x *= sc; v.y *= sc;
      tab[OFF_BF + i] = v;
    }
  }
}

// Build B1t[n][k] fp16: n=2q+c (780 rows), k=2k2+ri (2368, zero-padded past 2340).
__global__ __launch_bounds__(256) void k_buildB(const float2* __restrict__ tab, h16* __restrict__ B1t) {
  int n = blockIdx.x;
  int q = n >> 1, c = n & 1;
  int tid = threadIdx.x;
  __shared__ float2 t[1170];
  for (int j = tid; j < 1170; j += 256) t[j] = tab[OFF_T1170 + j];
  __syncthreads();
  h16* row = B1t + (size_t)n * KP1;
  for (int k2 = tid; k2 < 1184; k2 += 256) {
    h16x2 h;
    if (k2 < 1170) {
      unsigned m = ((unsigned)q * (unsigned)k2) % 1170u;
      float2 e = t[m];                 // (cos, sin) of +2pi m/1170
      h.x = (h16)(c ? e.y : e.x);      // ri=0 column
      h.y = (h16)(c ? e.x : -e.y);     // ri=1 column
    } else { h.x = (h16)0.f; h.y = (h16)0.f; }
    *(h16x2*)(row + 2 * k2) = h;
  }
}

// Build A2[p][k] fp16: p<211 rows, k=2k1+c (448, zero pad past 424). No SNORM (folded into FINAL).
__global__ __launch_bounds__(256) void k_buildA2(const float2* __restrict__ tab, h16* __restrict__ A2) {
  int p = blockIdx.x;
  int tid = threadIdx.x;
  __shared__ float2 t[422];
  for (int j = tid; j < 422; j += 256) t[j] = tab[OFF_T422 + j];
  __syncthreads();
  h16* row = A2 + (size_t)p * KP2;
  for (int k1 = tid; k1 < 224; k1 += 256) {
    h16x2 h; h.x = (h16)0.f; h.y = (h16)0.f;
    if (k1 < 212) {
      unsigned m = ((unsigned)p * (unsigned)k1) % 422u;
      float2 e = t[m];
      float cf = (k1 == 0 || k1 == 211) ? 1.f : 2.f;
      h.x = (h16)(cf * e.x);
      h.y = (h16)(-cf * e.y);
    }
    *(h16x2*)(row + 2 * k1) = h;
  }
}

// Forward row FFTs: rows of padded x -> length-1170 DFT via 3x pre-twiddled DFT-390.
__global__ __launch_bounds__(448) void k_rowfft(const float* __restrict__ x, const float2* __restrict__ tab,
                                                float2* __restrict__ X) {
  int i = blockIdx.x;  // < 211
  int tid = threadIdx.x;
  __shared__ float2 a0[390], a1[390], a2[390], b0[390], b1[390], b2[390];
  __shared__ float2 w390s[390];
  __shared__ float2 t1170s[780];
  for (int j = tid; j < 390; j += 448) w390s[j] = tab[OFF_W390 + j];
  for (int j = tid; j < 780; j += 448) t1170s[j] = tab[OFF_T1170 + j];
  __syncthreads();
  for (int j = tid; j < 390; j += 448) {
    float xv = 100.0f * x[i * 390 + j];
    a0[j] = make_float2(xv, 0.0f);
    float2 t1 = t1170s[j];
    a1[j] = make_float2(xv * t1.x, -xv * t1.y);
    float2 t2 = t1170s[2 * j];
    a2[j] = make_float2(xv * t2.x, -xv * t2.y);
  }
  __syncthreads();
  float2 X0 = make_float2(0,0), X1 = X0, X2 = X0;
  dft390x3<0>(a0, a1, a2, b0, b1, b2, w390s, tid, X0, X1, X2);
  if (tid < 390) {
    size_t base = (size_t)i * D2 + 3 * (size_t)tid;
    X[base + 0] = X0; X[base + 1] = X1; X[base + 2] = X2;
  }
}

// Forward column FFTs (8 per block) via 2x Bluestein-211. In-place in X.
__global__ __launch_bounds__(512) void k_colfft(const float2* __restrict__ tab, float2* __restrict__ X) {
  int tid = threadIdx.x;
  int q0 = blockIdx.x * 8;
  int ncols = min(8, D2 - q0);
  __shared__ float Xre[8][212], Xim[8][212];
  __shared__ float2 bufE[512], bufO[512];
  __shared__ float2 w512s[512], chirps[211], u422s[211];
  for (int j = tid; j < 512; j += 512) w512s[j] = tab[OFF_W512 + j];
  for (int j = tid; j < 211; j += 512) { chirps[j] = tab[OFF_CHIRP + j]; u422s[j] = tab[OFF_U422 + j]; }
  const float2* Bf = tab + OFF_BF;
  for (int idx = tid; idx < 211 * 8; idx += 512) {
    int i = idx >> 3, c = idx & 7;
    float2 v = make_float2(0.f, 0.f);
    if (c < ncols) v = X[(size_t)i * D2 + q0 + c];
    Xre[c][i] = v.x; Xim[c][i] = v.y;
  }
  __syncthreads();
  int g = tid >> 8, lt = tid & 255;
  float2* buf = g ? bufO : bufE;
  for (int c = 0; c < ncols; ++c) {
    #pragma unroll
    for (int s = 0; s < 2; ++s) {
      int i2 = lt + (s << 8);
      float2 v = make_float2(0.f, 0.f);
      if (i2 < 211) {
        v = make_float2(Xre[c][i2], Xim[c][i2]);
        if (g) v = cmulc(v, u422s[i2]);
        v = cmulc(v, chirps[i2]);
      }
      buf[i2] = v;
    }
    bluestein_core(buf, w512s, Bf, lt);
    #pragma unroll
    for (int s = 0; s < 2; ++s) {
      int i2 = lt + (s << 8);
      if (i2 < 211) {
        float2 r = cmulc(buf[i2], chirps[i2]);
        X[(size_t)(2 * i2 + g) * D2 + q0 + c] = r;
      }
    }
    __syncthreads();
  }
}

// Build A (stage1 GEMM LHS): A[fl][k1][2k2+ri] = (X[k1]*G_f[k1])*2^-10 fp16.
__global__ __launch_bounds__(256) void k_buildA(const float* __restrict__ Hr, const float* __restrict__ Hi,
                                                const float2* __restrict__ X, h16* __restrict__ A, int f0) {
  int k1 = blockIdx.x, fl = blockIdx.y, f = f0 + fl;
  int tid = threadIdx.x;
  int m1 = (422 - k1) % 422;
  size_t hb  = (size_t)f * (D1 * D2) + (size_t)k1 * D2;
  size_t hmb = (size_t)f * (D1 * D2) + (size_t)m1 * D2;
  const float2* Xr = X + (size_t)k1 * D2;
  h16* Arow = A + ((size_t)fl * 212 + k1) * KP1;
  for (int k2 = tid; k2 < 1170; k2 += 256) {
    int rk = k2 ? 1170 - k2 : 0;
    float gr = 0.5f * (Hr[hb + k2] + Hr[hmb + rk]);
    float gi = 0.5f * (Hi[hb + k2] - Hi[hmb + rk]);
    float2 xv = Xr[k2];
    float yr = (xv.x * gr - xv.y * gi) * SC_A;
    float yi = (xv.x * gi + xv.y * gr) * SC_A;
    h16x2 h; h.x = (h16)yr; h.y = (h16)yi;
    *(h16x2*)(Arow + 2 * k2) = h;
  }
  if (tid < 28) Arow[2340 + tid] = (h16)0.f;
}

// Stage1 MFMA GEMM: Z'[212 x 780] = A[212 x 2368] * B1t^T, fp16 in / fp32 acc / fp16 out.
// Block tile 128x128, 4 waves 2x2, wave 64x64 (16 MFMA 16x16x32 per K-chunk of 32).
__global__ __launch_bounds__(256) void k_gemm1(const h16* __restrict__ A, const h16* __restrict__ B1t,
                                               h16* __restrict__ Z) {
  int fl = blockIdx.y;
  int mt = blockIdx.x / 7, nt = blockIdx.x % 7;
  const int M0 = mt ? 84 : 0;                 // overlap tile (rows recomputed identically)
  const int N0 = (nt == 6) ? 652 : nt * 128;  // overlap tile in N
  int tid = threadIdx.x, wv = tid >> 6, ln = tid & 63;
  int l15 = ln & 15, l16 = ln >> 4;
  int wm = (wv >> 1) * 64, wn = (wv & 1) * 64;
  __shared__ __align__(16) h16 Alds[128 * 32];
  __shared__ __align__(16) h16 Blds[128 * 32];
  const char* Ag = (const char*)(A + (size_t)fl * 212 * KP1);
  const char* Bg = (const char*)B1t;
  f32x4 acc[4][4] = {};
  for (int kc = 0; kc < 74; ++kc) {
    int kb = kc * 64;  // byte offset within row
    __syncthreads();
    #pragma unroll
    for (int s = 0; s < 2; ++s) {
      int L = ((wv * 2 + s) * 64 + ln) * 16;
      int row = L >> 6, colb = L & 63;
      async16(Ag + (size_t)(M0 + row) * KB1 + kb + colb, (char*)Alds + (wv * 2 + s) * 1024);
      async16(Bg + (size_t)(N0 + row) * KB1 + kb + colb, (char*)Blds + (wv * 2 + s) * 1024);
    }
    __syncthreads();
    h16x8 af[4], bf[4];
    const h16x8* Av = (const h16x8*)Alds;
    const h16x8* Bv = (const h16x8*)Blds;
    #pragma unroll
    for (int i = 0; i < 4; ++i) af[i] = Av[(wm + i * 16 + l15) * 4 + l16];
    #pragma unroll
    for (int j = 0; j < 4; ++j) bf[j] = Bv[(wn + j * 16 + l15) * 4 + l16];
    #pragma unroll
    for (int i = 0; i < 4; ++i)
      #pragma unroll
      for (int j = 0; j < 4; ++j)
        acc[i][j] = __builtin_amdgcn_mfma_f32_16x16x32_f16(af[i], bf[j], acc[i][j], 0, 0, 0);
  }
  h16* Zf = Z + (size_t)fl * 212 * ZS2;
  #pragma unroll
  for (int i = 0; i < 4; ++i) {
    #pragma unroll
    for (int j = 0; j < 4; ++j) {
      #pragma unroll
      for (int r = 0; r < 4; ++r) {
        int m = M0 + wm + i * 16 + l16 * 4 + r;
        int n = N0 + wn + j * 16 + l15;
        Zf[(size_t)m * ZS2 + n] = (h16)acc[i][j][r];
      }
    }
  }
}

// Stage2 MFMA GEMM + fused power-mean epilogue.
// y'[211 x 390] = A2[211 x 448] * Z'^T-staged; out[f] += FINAL * sum(max(y'^2, TH)).
__global__ __launch_bounds__(256) void k_gemm2(const h16* __restrict__ A2, const h16* __restrict__ Z,
                                               float* __restrict__ out, int f0) {
  int fl = blockIdx.y, f = f0 + fl;
  int mt = blockIdx.x / 7, nt = blockIdx.x % 7;
  const int M0 = (mt == 3) ? 147 : mt * 64;
  const int pmin = (mt == 3) ? 192 : 0;      // ownership for overlap tile
  const int N0 = (nt == 6) ? 326 : nt * 64;
  const int qmin = (nt == 6) ? 384 : 0;
  int tid = threadIdx.x, wv = tid >> 6, ln = tid & 63;
  int l15 = ln & 15, l16 = ln >> 4;
  int wm = (wv >> 1) * 32, wn = (wv & 1) * 32;
  __shared__ __align__(16) h16 Alds[64 * 32];
  __shared__ __align__(16) h16 Blds[64 * 32];
  const char* Ag = (const char*)A2;
  const h16* Zf = Z + (size_t)fl * 212 * ZS2;
  f32x4 acc[2][2] = {};
  int brow = tid >> 4, bseg = tid & 15;
  for (int kc = 0; kc < 14; ++kc) {
    __syncthreads();
    {  // A tile: 64x32 via global_load_lds (1 issue/wave)
      int L = (wv * 64 + ln) * 16;
      int row = L >> 6, colb = L & 63;
      async16(Ag + (size_t)(M0 + row) * KB2 + kc * 64 + colb, (char*)Alds + wv * 1024);
    }
    {  // B tile: transpose-stage Z'[k1][2q+c] -> Blds[q^][k^]
      int k1r = kc * 16 + brow;
      uint2 u0 = make_uint2(0, 0), u1 = make_uint2(0, 0);
      if (k1r < 212) {
        const uint2* src = (const uint2*)(Zf + (size_t)k1r * ZS2 + 2 * N0 + bseg * 8);
        u0 = src[0]; u1 = src[1];
      }
      unsigned int w[4] = {u0.x, u0.y, u1.x, u1.y};
      unsigned short* Bs = (unsigned short*)Blds;
      #pragma unroll
      for (int h = 0; h < 4; ++h) {
        int qh = bseg * 4 + h;
        Bs[qh * 32 + 2 * brow + 0] = (unsigned short)(w[h] & 0xffffu);
        Bs[qh * 32 + 2 * brow + 1] = (unsigned short)(w[h] >> 16);
      }
    }
    __syncthreads();
    h16x8 af[2], bf[2];
    const h16x8* Av = (const h16x8*)Alds;
    const h16x8* Bv = (const h16x8*)Blds;
    af[0] = Av[(wm + l15) * 4 + l16];
    af[1] = Av[(wm + 16 + l15) * 4 + l16];
    bf[0] = Bv[(wn + l15) * 4 + l16];
    bf[1] = Bv[(wn + 16 + l15) * 4 + l16];
    #pragma unroll
    for (int i = 0; i < 2; ++i)
      #pragma unroll
      for (int j = 0; j < 2; ++j)
        acc[i][j] = __builtin_amdgcn_mfma_f32_16x16x32_f16(af[i], bf[j], acc[i][j], 0, 0, 0);
  }
  float accs = 0.f;
  #pragma unroll
  for (int i = 0; i < 2; ++i) {
    #pragma unroll
    for (int j = 0; j < 2; ++j) {
      #pragma unroll
      for (int r = 0; r < 4; ++r) {
        int p = M0 + wm + i * 16 + l16 * 4 + r;
        int q = N0 + wn + j * 16 + l15;
        if (p >= pmin && q >= qmin) {
          float y = acc[i][j][r];
          accs += fmaxf(y * y, TH_CL);
        }
      }
    }
  }
  for (int off = 32; off > 0; off >>= 1) accs += __shfl_down(accs, off, 64);
  __shared__ float wred[4];
  if (ln == 0) wred[wv] = accs;
  __syncthreads();
  if (tid == 0) atomicAdd(&out[f], (wred[0] + wred[1] + wred[2] + wred[3]) * FINAL);
}

extern "C" void kernel_launch(void* const* d_in, const int* in_sizes, int n_in,
                              void* d_out, int out_size, void* d_ws, size_t ws_size,
                              hipStream_t stream) {
  const float* x  = (const float*)d_in[0];
  const float* Hr = (const float*)d_in[1];
  const float* Hi = (const float*)d_in[2];
  float* out = (float*)d_out;
  char* base = (char*)d_ws;

  size_t off = 0;
  auto alloc = [&](size_t bytes) { size_t cur = off; off = (off + bytes + 255) & ~(size_t)255; return cur; };
  float2* tab = (float2*)(base + alloc(32768));
  float2* X   = (float2*)(base + alloc((size_t)D1 * D2 * sizeof(float2)));
  h16* B1t    = (h16*)(base + alloc((size_t)780 * KP1 * 2));
  h16* A2     = (h16*)(base + alloc((size_t)211 * KP2 * 2));
  size_t perA = (size_t)212 * KP1 * 2;   // 1,004,032 B
  size_t perZ = (size_t)212 * ZS2 * 2;   //   332,416 B
  long long avail = (long long)ws_size - (long long)off - 512;
  int chunk = (avail > 0) ? (int)(avail / (long long)(perA + perZ)) : 1;
  if (chunk < 1) chunk = 1;
  if (chunk > NF) chunk = NF;
  h16* A = (h16*)(base + alloc(perA * chunk));
  h16* Zp = (h16*)(base + alloc(perZ * chunk));

  k_init<<<dim3(1), dim3(512), 0, stream>>>(tab, out);
  k_buildB<<<dim3(780), dim3(256), 0, stream>>>(tab, B1t);
  k_buildA2<<<dim3(211), dim3(256), 0, stream>>>(tab, A2);
  k_rowfft<<<dim3(211), dim3(448), 0, stream>>>(x, tab, X);
  k_colfft<<<dim3(147), dim3(512), 0, stream>>>(tab, X);
  for (int f0 = 0; f0 < NF; f0 += chunk) {
    int nf = NF - f0;
    if (nf > chunk) nf = chunk;
    k_buildA<<<dim3(212, nf), dim3(256), 0, stream>>>(Hr, Hi, X, A, f0);
    k_gemm1<<<dim3(14, nf), dim3(256), 0, stream>>>(A, B1t, Zp);
    k_gemm2<<<dim3(28, nf), dim3(256), 0, stream>>>(A2, Zp, out, f0);
  }
}